// Round 7
// baseline (896.765 us; speedup 1.0000x reference)
//
#include <hip/hip_runtime.h>

// Problem constants (fixed by reference)
#define NN   50000
#define DD   16
#define FFE  256
#define HH   8
#define DHH  32
#define RR   20
#define HOPN 10

typedef unsigned short u16;
typedef unsigned int   u32;
typedef __attribute__((ext_vector_type(8))) short  short8;   // 8 bf16 = 4 VGPRs
typedef __attribute__((ext_vector_type(4))) float  floatx4;

__device__ __forceinline__ float b2f(u16 u){ return __uint_as_float(((u32)u)<<16); }
__device__ __forceinline__ u16 f2b(float f){
  u32 x = __float_as_uint(f);
  u32 r = (x + 0x7fffu + ((x>>16)&1u)) >> 16;   // RNE
  return (u16)r;
}
// bf16 pair unpack from u32 (little-endian: low half = even channel)
__device__ __forceinline__ float blo(u32 u){ return __uint_as_float(u << 16); }
__device__ __forceinline__ float bhi(u32 u){ return __uint_as_float(u & 0xffff0000u); }

// ---------------------------------------------------------------------------
// castw: one-off cast+transpose of value-path weights to bf16 [N][K] layout.
// ---------------------------------------------------------------------------
__global__ __launch_bounds__(256) void castw_kernel(
    const float* __restrict__ We, const float* __restrict__ W1,
    const float* __restrict__ W2,
    u16* __restrict__ Wet, u16* __restrict__ W1t, u16* __restrict__ W2t)
{
  int tid = blockIdx.x*256 + threadIdx.x;
  if (tid < 256*256) {                       // W_ent [256][256] -> Wet[n][k]
    int k = tid >> 8, n = tid & 255;
    Wet[n*256 + k] = f2b(We[tid]);
  } else if (tid < 256*256 + 256*1024) {     // W1 [256][1024] -> W1t[n][k]
    int s = tid - 65536;
    int k = s >> 10, n = s & 1023;
    W1t[n*256 + k] = f2b(W1[s]);
  } else if (tid < 589824) {                 // W2 [1024][256] -> W2t[n][k]
    int s = tid - 327680;
    int k = s >> 8, n = s & 255;
    W2t[n*1024 + k] = f2b(W2[s]);
  }
}

// ---------------------------------------------------------------------------
// prep: blocks 0..19 -> LN(rel_feat[r]) @ W_rel -> er[r,h]  (fp64, selection)
//       block 20     -> fold attn into Wc[256][16]: cols 0..7 = W_head·attn_h,
//                       cols 8..15 = W_tail·attn_t.
// ---------------------------------------------------------------------------
__global__ __launch_bounds__(256) void prep_kernel(
    const float* __restrict__ rel_feat,
    const float* __restrict__ W_head, const float* __restrict__ W_tail,
    const float* __restrict__ W_rel,
    const float* __restrict__ attn_h, const float* __restrict__ attn_t,
    const float* __restrict__ attn_r,
    const float* __restrict__ lng, const float* __restrict__ lnb,
    double* __restrict__ Wc, double* __restrict__ er)
{
  int t = threadIdx.x;
  if (blockIdx.x == RR) {
    for (int h = 0; h < HH; h++) {
      double sh = 0.0, st = 0.0;
      #pragma unroll
      for (int c = 0; c < DHH; c++) {
        int j = h*DHH + c;
        sh += (double)W_head[t*FFE + j] * (double)attn_h[j];
        st += (double)W_tail[t*FFE + j] * (double)attn_t[j];
      }
      Wc[t*16 + h]     = sh;
      Wc[t*16 + 8 + h] = st;
    }
    return;
  }
  int r = blockIdx.x;
  __shared__ double red[8];
  __shared__ double rln[256];
  double v = (double)rel_feat[r*FFE + t];
  double s = v, q = v*v;
  #pragma unroll
  for (int o = 32; o; o >>= 1) { s += __shfl_xor(s, o, 64); q += __shfl_xor(q, o, 64); }
  if ((t & 63) == 0) { red[t>>6] = s; red[4 + (t>>6)] = q; }
  __syncthreads();
  double stot = red[0]+red[1]+red[2]+red[3];
  double qtot = red[4]+red[5]+red[6]+red[7];
  double mean = stot * (1.0/256.0);
  double var  = qtot * (1.0/256.0) - mean*mean;
  double rstd = 1.0 / sqrt(var + 1e-5);
  rln[t] = (v - mean) * rstd * (double)lng[t] + (double)lnb[t];
  __syncthreads();
  double acc = 0.0;
  for (int k = 0; k < 256; k++) acc += rln[k] * (double)W_rel[k*FFE + t];
  double p = acc * (double)attn_r[t];
  #pragma unroll
  for (int o = 16; o; o >>= 1) p += __shfl_down(p, o, 32);
  if ((t & 31) == 0) er[r*HH + (t>>5)] = p;
}

// ---------------------------------------------------------------------------
// logits v4: zero LDS. One wave per ROW PAIR; lane l holds x-cols
// {l, l+64, l+128, l+192}. Phase 2: 16 fp64 accumulators per row, then a
// REDUCE-SCATTER (halve the exchanged set per level: 8+4+2+1 slots, then
// 2 broadcast levels) instead of a full 16-wide butterfly — ~34 DS ops/row
// vs 192 (v3's DS-pipe bound). fp64 order change ~1e-16 << min top-k gap.
// ---------------------------------------------------------------------------
__global__ __launch_bounds__(256) void logits_kernel(
    const float* __restrict__ ent,
    const float* __restrict__ lng, const float* __restrict__ lnb,
    const double* __restrict__ Wc,
    u16* __restrict__ xb, double* __restrict__ eh, double* __restrict__ et)
{
  int tid = threadIdx.x;
  int w = tid >> 6, l = tid & 63;
  int rowA = blockIdx.x*8 + w*2;
  int rowB = rowA + 1;
  float gg[4], bbv[4];
  #pragma unroll
  for (int j = 0; j < 4; j++) { gg[j] = lng[l + 64*j]; bbv[j] = lnb[l + 64*j]; }
  double xA[4], xB[4];
  #pragma unroll
  for (int j = 0; j < 4; j++) xA[j] = (double)ent[(size_t)rowA*FFE + l + 64*j];
  #pragma unroll
  for (int j = 0; j < 4; j++) xB[j] = (double)ent[(size_t)rowB*FFE + l + 64*j];
  double sA = xA[0]+xA[1]+xA[2]+xA[3];
  double sB = xB[0]+xB[1]+xB[2]+xB[3];
  double qA = xA[0]*xA[0]+xA[1]*xA[1]+xA[2]*xA[2]+xA[3]*xA[3];
  double qB = xB[0]*xB[0]+xB[1]*xB[1]+xB[2]*xB[2]+xB[3]*xB[3];
  #pragma unroll
  for (int o = 32; o; o >>= 1) {
    sA += __shfl_xor(sA, o, 64); qA += __shfl_xor(qA, o, 64);
    sB += __shfl_xor(sB, o, 64); qB += __shfl_xor(qB, o, 64);
  }
  double mA = sA * (1.0/256.0), mB = sB * (1.0/256.0);
  double vA = qA * (1.0/256.0) - mA*mA, vB = qB * (1.0/256.0) - mB*mB;
  double rsA = 1.0 / sqrt(vA + 1e-5), rsB = 1.0 / sqrt(vB + 1e-5);
  #pragma unroll
  for (int j = 0; j < 4; j++) {
    double yA = (xA[j]-mA)*rsA*(double)gg[j] + (double)bbv[j];
    double yB = (xB[j]-mB)*rsB*(double)gg[j] + (double)bbv[j];
    xA[j] = yA; xB[j] = yB;
    xb[(size_t)rowA*FFE + l + 64*j] = f2b((float)yA);
    xb[(size_t)rowB*FFE + l + 64*j] = f2b((float)yB);
  }
  double accA[16], accB[16];
  #pragma unroll
  for (int o = 0; o < 16; o++) { accA[o] = 0.0; accB[o] = 0.0; }
  #pragma unroll
  for (int j = 0; j < 4; j++) {
    int k = l + 64*j;
    const double2* wp = (const double2*)(Wc + (size_t)k*16);
    double wv[16];
    #pragma unroll
    for (int u = 0; u < 8; u++) { double2 tv = wp[u]; wv[2*u] = tv.x; wv[2*u+1] = tv.y; }
    #pragma unroll
    for (int o = 0; o < 16; o++) {
      accA[o] = fma(xA[j], wv[o], accA[o]);
      accB[o] = fma(xB[j], wv[o], accB[o]);
    }
  }
  // ---- reduce-scatter over 64 lanes, 16 outputs ----
  int b0 = l & 1, b1 = (l>>1)&1, b2 = (l>>2)&1, b3 = (l>>3)&1;
  double r1A[8], r1B[8];
  #pragma unroll
  for (int s = 0; s < 8; s++) {            // level 1 (xor 1): keep 8
    double kA = b0 ? accA[8+s] : accA[s];
    double dA = b0 ? accA[s]   : accA[8+s];
    double kB = b0 ? accB[8+s] : accB[s];
    double dB = b0 ? accB[s]   : accB[8+s];
    r1A[s] = kA + __shfl_xor(dA, 1, 64);
    r1B[s] = kB + __shfl_xor(dB, 1, 64);
  }
  double r2A[4], r2B[4];
  #pragma unroll
  for (int s = 0; s < 4; s++) {            // level 2 (xor 2): keep 4
    double kA = b1 ? r1A[4+s] : r1A[s];
    double dA = b1 ? r1A[s]   : r1A[4+s];
    double kB = b1 ? r1B[4+s] : r1B[s];
    double dB = b1 ? r1B[s]   : r1B[4+s];
    r2A[s] = kA + __shfl_xor(dA, 2, 64);
    r2B[s] = kB + __shfl_xor(dB, 2, 64);
  }
  double r3A[2], r3B[2];
  #pragma unroll
  for (int s = 0; s < 2; s++) {            // level 3 (xor 4): keep 2
    double kA = b2 ? r2A[2+s] : r2A[s];
    double dA = b2 ? r2A[s]   : r2A[2+s];
    double kB = b2 ? r2B[2+s] : r2B[s];
    double dB = b2 ? r2B[s]   : r2B[2+s];
    r3A[s] = kA + __shfl_xor(dA, 4, 64);
    r3B[s] = kB + __shfl_xor(dB, 4, 64);
  }
  // level 4 (xor 8): keep 1
  double k4A = b3 ? r3A[1] : r3A[0];
  double d4A = b3 ? r3A[0] : r3A[1];
  double k4B = b3 ? r3B[1] : r3B[0];
  double d4B = b3 ? r3B[0] : r3B[1];
  double fA4 = k4A + __shfl_xor(d4A, 8, 64);
  double fB4 = k4B + __shfl_xor(d4B, 8, 64);
  // levels 5,6: sum the 4 replicas (lanes l, l^16, l^32, l^48 share output)
  fA4 += __shfl_xor(fA4, 16, 64);  fB4 += __shfl_xor(fB4, 16, 64);
  fA4 += __shfl_xor(fA4, 32, 64);  fB4 += __shfl_xor(fB4, 32, 64);
  // output index owned by this lane: o = 8*b0 + 4*b1 + 2*b2 + b3
  int o = (b0<<3) | (b1<<2) | (b2<<1) | b3;
  if (l < 16) {
    if (o < 8) eh[(size_t)rowA*HH + o] = fA4;
    else       et[(size_t)rowA*HH + (o-8)] = fA4;
  } else if (l < 32) {
    if (o < 8) eh[(size_t)rowB*HH + o] = fB4;
    else       et[(size_t)rowB*HH + (o-8)] = fB4;
  }
}

// ---------------------------------------------------------------------------
// gemm: C[M,N] = A[M,K]bf16 @ B[N,K]bf16 (B pre-transposed), MFMA 16x16x32.
// 128x128 tile, BK=32, 256 threads (4 waves, each 32 rows x 128 cols).
// EPI 0: bf16 store. EPI 1: relu(v+bias) bf16. EPI 2: v+bias+feat+ent fp32.
// ---------------------------------------------------------------------------
template<int EPI>
__global__ __launch_bounds__(256) void gemm_kernel(
    const u16* __restrict__ A, const u16* __restrict__ B,
    const float* __restrict__ bias,
    const u16* __restrict__ feat, const float* __restrict__ ent,
    u16* __restrict__ Obf, float* __restrict__ Of,
    int M, int N, int K)
{
  __shared__ u16 As[128][40];
  __shared__ u16 Bs[128][40];
  int t = threadIdx.x;
  int i0 = blockIdx.x * 128;
  int n0 = blockIdx.y * 128;
  int w = t >> 6, l = t & 63;
  int cr = t >> 2;              // staging row 0..63 (and +64)
  int cc = (t & 3) * 8;         // staging k-offset {0,8,16,24}
  int ga0 = min(i0 + cr, M-1);  // clamp M-boundary reads (stores predicated)
  int ga1 = min(i0 + cr + 64, M-1);
  int gb0 = n0 + cr;
  int gb1 = n0 + cr + 64;
  floatx4 acc[2][8];
  #pragma unroll
  for (int mt = 0; mt < 2; mt++)
    #pragma unroll
    for (int nt = 0; nt < 8; nt++) acc[mt][nt] = (floatx4){0.f,0.f,0.f,0.f};
  int ln = l & 15, lq = (l >> 4) * 8;
  for (int k0 = 0; k0 < K; k0 += 32) {
    __syncthreads();
    *(uint4*)&As[cr][cc]      = *(const uint4*)&A[(size_t)ga0*K + k0 + cc];
    *(uint4*)&As[cr+64][cc]   = *(const uint4*)&A[(size_t)ga1*K + k0 + cc];
    *(uint4*)&Bs[cr][cc]      = *(const uint4*)&B[(size_t)gb0*K + k0 + cc];
    *(uint4*)&Bs[cr+64][cc]   = *(const uint4*)&B[(size_t)gb1*K + k0 + cc];
    __syncthreads();
    short8 bfr[8];
    #pragma unroll
    for (int nt = 0; nt < 8; nt++) bfr[nt] = *(const short8*)&Bs[nt*16 + ln][lq];
    #pragma unroll
    for (int mt = 0; mt < 2; mt++) {
      short8 afr = *(const short8*)&As[w*32 + mt*16 + ln][lq];
      #pragma unroll
      for (int nt = 0; nt < 8; nt++)
        acc[mt][nt] = __builtin_amdgcn_mfma_f32_16x16x32_bf16(afr, bfr[nt], acc[mt][nt], 0, 0, 0);
    }
  }
  int lr = (l >> 4) * 4;        // C/D layout: col=lane&15, row=(lane>>4)*4+reg
  #pragma unroll
  for (int mt = 0; mt < 2; mt++) {
    #pragma unroll
    for (int nt = 0; nt < 8; nt++) {
      int col = n0 + nt*16 + ln;
      #pragma unroll
      for (int r = 0; r < 4; r++) {
        int row = i0 + w*32 + mt*16 + lr + r;
        if (row < M) {
          float v = acc[mt][nt][r];
          if (EPI == 0) {
            Obf[(size_t)row*N + col] = f2b(v);
          } else if (EPI == 1) {
            v += bias[col];
            Obf[(size_t)row*N + col] = f2b(v > 0.f ? v : 0.f);
          } else {
            v += bias[col] + b2f(feat[(size_t)row*FFE + col]) + ent[(size_t)row*FFE + col];
            Of[(size_t)row*N + col] = v;
          }
        }
      }
    }
  }
}

// ---------------------------------------------------------------------------
// edge: per (i,h): e_d = leaky(eh[src]+et+er[rid]) in fp64; top-5 (+1 tie slot);
//       weights = exp(e-max)/sum_top5, prescaled by (1-ALPHA)=0.9.
// Output: packed 64B record per (i,h): {idx[6] i32, w[6] f32, 16B pad}.
// ---------------------------------------------------------------------------
__global__ __launch_bounds__(256) void edge_kernel(
    const int* __restrict__ src, const int* __restrict__ rid,
    const double* __restrict__ eh, const double* __restrict__ et,
    const double* __restrict__ er,
    uint4* __restrict__ rec)
{
  int tid = blockIdx.x*256 + threadIdx.x;
  if (tid >= NN*HH) return;
  int i = tid >> 3, h = tid & 7;
  double bet = et[tid];
  double e[16]; int sj[16];
  #pragma unroll
  for (int d = 0; d < 16; d++) {
    int s = src[i*DD + d];
    int rv = rid[i*DD + d];
    sj[d] = s;
    double v = eh[s*HH + h] + bet + er[rv*HH + h];
    e[d] = (v > 0.0) ? v : 0.2 * v;
  }
  u32 mask = 0; double vs[5]; int js[5];
  #pragma unroll
  for (int k = 0; k < 5; k++) {
    double best = -1e300; int bj = 0, bd = 0;
    #pragma unroll
    for (int d = 0; d < 16; d++) {
      bool c = (((mask>>d)&1u) == 0u) && (e[d] > best);
      if (c) { best = e[d]; bj = sj[d]; bd = d; }
    }
    mask |= (1u << bd); vs[k] = best; js[k] = bj;
  }
  double kth = vs[4];
  int j6 = 0; bool f6 = false;
  #pragma unroll
  for (int d = 0; d < 16; d++) {
    if ((((mask>>d)&1u) == 0u) && (e[d] == kth) && !f6) { j6 = sj[d]; f6 = true; }
  }
  float m0 = (float)vs[0];
  float ex[5], ssum = 0.f;
  #pragma unroll
  for (int k = 0; k < 5; k++) { ex[k] = __expf((float)vs[k] - m0); ssum += ex[k]; }
  float inv = 0.9f / ssum;
  float w5 = f6 ? ex[4]*inv : 0.f;
  size_t rb = (size_t)tid * 4;
  rec[rb+0] = make_uint4((u32)js[0], (u32)js[1], (u32)js[2], (u32)js[3]);
  rec[rb+1] = make_uint4((u32)js[4], (u32)j6,
                         __float_as_uint(ex[0]*inv), __float_as_uint(ex[1]*inv));
  rec[rb+2] = make_uint4(__float_as_uint(ex[2]*inv), __float_as_uint(ex[3]*inv),
                         __float_as_uint(ex[4]*inv), __float_as_uint(w5));
}

// ---------------------------------------------------------------------------
// diff v4: one hop, 16B-granularity. 4 lanes per (i,h) group, each lane
// gathers dwordx4 (16B = 8 channels): one gather instr covers 16 groups.
// idx/w via 3 broadcast b128 reads of the 64B record. 8 nodes/block,
// grid 6250 => TLP for latency hiding. ~11 VMEM instr/wave (was ~34 for
// 4x fewer groups).
// ---------------------------------------------------------------------------
__global__ __launch_bounds__(256) void diff_kernel(
    const u16* __restrict__ fold, const u16* __restrict__ fe,
    const uint4* __restrict__ rec, u16* __restrict__ fnew)
{
  int tid = threadIdx.x;
  int g = tid >> 2, q = tid & 3;       // 64 groups/block, 4 lanes/group
  int i = blockIdx.x*8 + (g >> 3);
  int h = g & 7;
  const uint4* f4  = (const uint4*)fold;
  const uint4* fe4 = (const uint4*)fe;
  uint4* fn4 = (uint4*)fnew;
  size_t rb = ((size_t)i*HH + h) * 4;
  uint4 ra = rec[rb], rbv = rec[rb+1], rc = rec[rb+2];
  int idx[6] = {(int)ra.x,(int)ra.y,(int)ra.z,(int)ra.w,(int)rbv.x,(int)rbv.y};
  float wv[6];
  wv[0]=__uint_as_float(rbv.z); wv[1]=__uint_as_float(rbv.w);
  wv[2]=__uint_as_float(rc.x);  wv[3]=__uint_as_float(rc.y);
  wv[4]=__uint_as_float(rc.z);  wv[5]=__uint_as_float(rc.w);
  int co = h*4 + q;                    // uint4 offset within row (32 per row)
  uint4 fv = fe4[(size_t)i*32 + co];
  float a0 = 0.1f*blo(fv.x), a1 = 0.1f*bhi(fv.x);
  float a2 = 0.1f*blo(fv.y), a3 = 0.1f*bhi(fv.y);
  float a4 = 0.1f*blo(fv.z), a5 = 0.1f*bhi(fv.z);
  float a6 = 0.1f*blo(fv.w), a7 = 0.1f*bhi(fv.w);
  #pragma unroll
  for (int k = 0; k < 5; k++) {
    uint4 v = f4[(size_t)idx[k]*32 + co];
    float wk = wv[k];
    a0 += wk*blo(v.x); a1 += wk*bhi(v.x);
    a2 += wk*blo(v.y); a3 += wk*bhi(v.y);
    a4 += wk*blo(v.z); a5 += wk*bhi(v.z);
    a6 += wk*blo(v.w); a7 += wk*bhi(v.w);
  }
  if (wv[5] != 0.f) {                  // tie slot: rare, uniform per quad
    uint4 v = f4[(size_t)idx[5]*32 + co];
    float wk = wv[5];
    a0 += wk*blo(v.x); a1 += wk*bhi(v.x);
    a2 += wk*blo(v.y); a3 += wk*bhi(v.y);
    a4 += wk*blo(v.z); a5 += wk*bhi(v.z);
    a6 += wk*blo(v.w); a7 += wk*bhi(v.w);
  }
  uint4 o;
  o.x = (u32)f2b(a0) | ((u32)f2b(a1) << 16);
  o.y = (u32)f2b(a2) | ((u32)f2b(a3) << 16);
  o.z = (u32)f2b(a4) | ((u32)f2b(a5) << 16);
  o.w = (u32)f2b(a6) | ((u32)f2b(a7) << 16);
  fn4[(size_t)i*32 + co] = o;
}

// ---------------------------------------------------------------------------
// ln_ff: y = bf16( LN(feat+ent) ).  One wave per row, lane holds 4 elems.
// ---------------------------------------------------------------------------
__global__ __launch_bounds__(256) void ln_ff_kernel(
    const u16* __restrict__ feat, const float* __restrict__ ent,
    const float* __restrict__ g, const float* __restrict__ b,
    u16* __restrict__ y)
{
  int w = threadIdx.x >> 6, l = threadIdx.x & 63;
  int row = blockIdx.x*4 + w;
  float4 e4 = *(const float4*)&ent[row*FFE + l*4];
  ushort4 fv = *(const ushort4*)&feat[row*FFE + l*4];
  float v0 = b2f(fv.x)+e4.x, v1 = b2f(fv.y)+e4.y;
  float v2 = b2f(fv.z)+e4.z, v3 = b2f(fv.w)+e4.w;
  float s = v0+v1+v2+v3;
  float q = v0*v0 + v1*v1 + v2*v2 + v3*v3;
  #pragma unroll
  for (int o = 32; o; o >>= 1) { s += __shfl_xor(s, o, 64); q += __shfl_xor(q, o, 64); }
  float mean = s * (1.f/256.f);
  float var  = q * (1.f/256.f) - mean*mean;
  float rstd = rsqrtf(var + 1e-5f);
  float4 g4 = *(const float4*)&g[l*4];
  float4 b4 = *(const float4*)&b[l*4];
  ushort4 o4;
  o4.x = f2b((v0-mean)*rstd*g4.x + b4.x);
  o4.y = f2b((v1-mean)*rstd*g4.y + b4.y);
  o4.z = f2b((v2-mean)*rstd*g4.z + b4.z);
  o4.w = f2b((v3-mean)*rstd*g4.w + b4.w);
  *(ushort4*)&y[row*FFE + l*4] = o4;
}

// ---------------------------------------------------------------------------
extern "C" void kernel_launch(void* const* d_in, const int* in_sizes, int n_in,
                              void* d_out, int out_size, void* d_ws, size_t ws_size,
                              hipStream_t stream)
{
  const float* ent      = (const float*)d_in[0];
  const float* rel      = (const float*)d_in[1];
  const float* W_head   = (const float*)d_in[2];
  const float* W_tail   = (const float*)d_in[3];
  const float* W_ent    = (const float*)d_in[4];
  const float* W_rel    = (const float*)d_in[5];
  const float* attn_h   = (const float*)d_in[6];
  const float* attn_t   = (const float*)d_in[7];
  const float* attn_r   = (const float*)d_in[8];
  const float* ln_ent_g = (const float*)d_in[9];
  const float* ln_ent_b = (const float*)d_in[10];
  const float* ln_rel_g = (const float*)d_in[11];
  const float* ln_rel_b = (const float*)d_in[12];
  const float* ln_ff_g  = (const float*)d_in[13];
  const float* ln_ff_b  = (const float*)d_in[14];
  const float* W1       = (const float*)d_in[15];
  const float* b1       = (const float*)d_in[16];
  const float* W2       = (const float*)d_in[17];
  const float* b2       = (const float*)d_in[18];
  const int* src        = (const int*)d_in[19];
  const int* rid        = (const int*)d_in[20];
  float* out = (float*)d_out;

  // Workspace layout (same footprint as r5/r6, end 154,816,512):
  //  h1 (102.4 MB) aliases [0,102.4M) — everything there dead before gemm1.
  //  rec (25.6 MB) aliases xb — xb dead after proj-gemm, edge runs after.
  char* w = (char*)d_ws;
  double* er64 = (double*)(w + 0);            // 1.3 KB   (dead after edge)
  double* Wc   = (double*)(w + 4096);         // 32 KB    (dead after logits)
  double* eh64 = (double*)(w + 36864);        // 3.2 MB   (dead after edge)
  double* et64 = (double*)(w + 3236864);      // 3.2 MB
  u16*    xb   = (u16*)  (w + 6436864);       // 25.6 MB  (dead after proj)
  uint4*  rec  = (uint4*)(w + 6436864);       // 25.6 MB  alias xb (edge->hops)
  u16*    fe   = (u16*)  (w + 32036864);      // 25.6 MB  (dead after hops)
  u16*    fA   = (u16*)  (w + 57636864);      // 25.6 MB  (dead after hops)
  u16*    h1   = (u16*)  (w + 0);             // 102.4 MB alias, gemm1->gemm2
  u16*    fB   = (u16*)  (w + 102436864);     // 25.6 MB  (final feat, live to end)
  u16*    y    = (u16*)  (w + 128036864);     // 25.6 MB
  u16*    Wet  = (u16*)  (w + 153636864);     // 128 KB
  u16*    W1t  = (u16*)  (w + 153767936);     // 512 KB
  u16*    W2t  = (u16*)  (w + 154292224);     // 512 KB  (end 154,816,512)

  castw_kernel<<<2304, 256, 0, stream>>>(W_ent, W1, W2, Wet, W1t, W2t);
  prep_kernel<<<RR+1, 256, 0, stream>>>(rel, W_head, W_tail, W_rel,
                                        attn_h, attn_t, attn_r,
                                        ln_rel_g, ln_rel_b, Wc, er64);
  logits_kernel<<<NN/8, 256, 0, stream>>>(ent, ln_ent_g, ln_ent_b, Wc,
                                          xb, eh64, et64);
  // proj: fe = xb @ Wet   (must complete before edge overwrites rec=xb)
  {
    dim3 g((NN + 127)/128, 2);
    gemm_kernel<0><<<g, 256, 0, stream>>>(xb, Wet, nullptr, nullptr, nullptr,
                                          fe, nullptr, NN, 256, 256);
  }
  edge_kernel<<<(NN*HH + 255)/256, 256, 0, stream>>>(src, rid, eh64, et64, er64,
                                                     rec);
  // 10 hops, one dispatch each (TLP >> fusion: round-4 lesson).
  const u16* cur = fe;
  u16* bufs[2] = { fA, fB };
  for (int hop = 0; hop < HOPN; hop++) {
    u16* nxt = bufs[hop & 1];
    diff_kernel<<<NN/8, 256, 0, stream>>>(cur, fe, rec, nxt);
    cur = nxt;                                 // final cur == fB (10 hops)
  }
  ln_ff_kernel<<<NN/4, 256, 0, stream>>>(cur, ent, ln_ff_g, ln_ff_b, y);
  {
    dim3 g((NN + 127)/128, 8);                 // h1 = relu(y@W1 + b1)
    gemm_kernel<1><<<g, 256, 0, stream>>>(y, W1t, b1, nullptr, nullptr,
                                          h1, nullptr, NN, 1024, 256);
  }
  {
    dim3 g((NN + 127)/128, 2);                 // out = h1@W2 + b2 + feat + ent
    gemm_kernel<2><<<g, 256, 0, stream>>>(h1, W2t, b2, cur, ent,
                                          nullptr, out, NN, 256, 1024);
  }
}